// Round 12
// baseline (581.931 us; speedup 1.0000x reference)
//
#include <hip/hip_runtime.h>
#include <stdint.h>

// ---------------------------------------------------------------------------
// UpProj block. Inputs fp32 or bf16 (runtime-detected); compute bf16 MFMA,
// fp32 accumulate; output dtype follows input dtype.
//  unpool(4 convs)x2: per conv-CLASS GEMMs packed into one launch.
//    class A (3,3): M=512, K=4608 | B (2,3): K=3072 | C (3,2): K=3072
//    | D (2,2): K=2048   (N=16384)
//  conv9 == GEMM M=256, K=2304, N=65536.
//  R11 (kept): m97-class occupancy GEMM at 906 TF (MfmaUtil 41%, structural
//  ceiling of the 128^2 2-barrier form; 256^2 8-phase ports all regressed).
//  R13 (kept): coalesced LDS-transpose pad_x/u_fill/pack_w.
//  R15/R16 (kept): split gemm symbols, fused border-zero, launch merges,
//  launch_bounds (256,4) (5 blocks/CU spills acc: VGPR 48, WRITE x13).
//  R17: BN stats fused into GEMM epilogues. bn_stats2/bn_stats re-read
//  100 MB the epilogues had in registers; now each block shuffle+LDS-reduces
//  its own n-slice into a deterministic per-block partial record (no
//  atomics), and 1-2-block bn_finalize kernels produce (scale,shift).
//  (R18 resubmit: R17 hit GPUAcquisitionTimeout, never measured.)
// ---------------------------------------------------------------------------

typedef __bf16 bf16x8 __attribute__((ext_vector_type(8)));
typedef float floatx4 __attribute__((ext_vector_type(4)));

typedef __attribute__((address_space(3))) uint32_t lds32_t;
typedef __attribute__((address_space(1))) const uint32_t glb32_t;

__device__ __forceinline__ void load_lds16(const uint16_t* g, uint16_t* l) {
  // async global->LDS: per-lane global addr, LDS dest = wave-uniform base + lane*16B
  __builtin_amdgcn_global_load_lds((glb32_t*)g, (lds32_t*)l, 16, 0, 0);
}

__device__ __forceinline__ float bf2f(uint32_t u) {
  union { uint32_t i; float f; } v;
  v.i = u << 16;
  return v.f;
}
__device__ __forceinline__ uint16_t f2bf(float f) {
  union { float f; uint32_t i; } v;
  v.f = f;
  uint32_t r = v.i + 0x7fff + ((v.i >> 16) & 1);  // RNE
  return (uint16_t)(r >> 16);
}
__device__ __forceinline__ float load_in(const void* p, size_t i, bool isbf) {
  return isbf ? bf2f(((const uint16_t*)p)[i]) : ((const float*)p)[i];
}

// class geometry helpers (cls 0=A,1=B,2=C,3=D; ey=cls&1, ex=cls>>1)
__device__ __forceinline__ int cls_ntaps(int cls) { return cls == 0 ? 9 : (cls == 3 ? 4 : 6); }
__device__ __forceinline__ size_t cls_off(int cls) {
  // element offsets of per-class W blocks: 512*{4608,3072,3072,2048} prefix
  return cls == 0 ? 0u : (cls == 1 ? 2359296u : (cls == 2 ? 3932160u : 5505024u));
}
__device__ __forceinline__ void cls_tap(int cls, int r, int& dy, int& dx) {
  if (cls >= 2) { dy = r >> 1; dx = r & 1; }        // kw=2 classes
  else { dy = r / 3; dx = r - 3 * (r / 3); }        // kw=3 classes
}

// ---------------- dtype detector ----------------
__global__ void detect_dtype(const uint32_t* __restrict__ xw, uint32_t* __restrict__ flag) {
  int t = threadIdx.x;
  int cnt = 0;
#pragma unroll
  for (int k = 0; k < 16; ++k) {
    uint32_t u = xw[t + k * 256];
    uint32_t e = (u >> 7) & 0xFF;
    cnt += (e >= 100 && e <= 140) ? 1 : 0;
  }
  __shared__ int rs[256];
  rs[t] = cnt;
  __syncthreads();
  for (int o = 128; o > 0; o >>= 1) {
    if (t < o) rs[t] += rs[t + o];
    __syncthreads();
  }
  if (t == 0) flag[0] = (rs[0] > 2048) ? 1u : 0u;  // 1 = bf16 inputs
}

// ---------------- weight packing: LDS permute, coalesced both sides --------
// One block per m (branch,cout). Load the 12800-elem weight slice (4 classes,
// source order cin*ntaps+tap) coalesced into LDS, then write packed rows
// (kk = r*512+cin) coalesced to Wp.
__global__ __launch_bounds__(256) void pack_w_unpool(
    const void* wa, const void* wb, const void* wc, const void* wd,
    const void* we, const void* wf, const void* wg, const void* wh,
    const uint32_t* __restrict__ flag, uint16_t* __restrict__ Wp) {
  const void* ws[8] = {wa, wb, wc, wd, we, wf, wg, wh};  // branch0 A,B,C,D; branch1 A,B,C,D
  __shared__ uint16_t wl[12800];
  const bool isbf = flag[0] != 0;
  const int t = threadIdx.x;
  const int m = blockIdx.x;  // 0..511
  const int branch = m >> 8, cout = m & 255;
  int base = 0;
#pragma unroll
  for (int cls = 0; cls < 4; ++cls) {
    const int ntap = cls_ntaps(cls);
    const int cnt = 512 * ntap;
    const void* src = ws[branch * 4 + cls];
    const size_t s0 = (size_t)cout * cnt;
    for (int idx = t; idx < cnt; idx += 256)
      wl[base + idx] = f2bf(load_in(src, s0 + idx, isbf));
    base += cnt;
  }
  __syncthreads();
  for (int kc = t; kc < 12800; kc += 256) {
    int cls, kk, b2, ntap;
    if (kc < 4608) { cls = 0; kk = kc; b2 = 0; ntap = 9; }
    else if (kc < 7680) { cls = 1; kk = kc - 4608; b2 = 4608; ntap = 6; }
    else if (kc < 10752) { cls = 2; kk = kc - 7680; b2 = 7680; ntap = 6; }
    else { cls = 3; kk = kc - 10752; b2 = 10752; ntap = 4; }
    const int r = kk >> 9, cin = kk & 511;
    const int Kcls = ntap << 9;
    Wp[cls_off(cls) + (size_t)m * Kcls + kk] = wl[b2 + cin * ntap + r];
  }
}

// pack_w9 + pack_bias fused. bpk layout: [cls][branch][cout] = bpk[bx*256+c]
__global__ void pack_w9b(const void* __restrict__ w9,
                         const void* b1, const void* b2, const void* b3, const void* b4,
                         const void* b5, const void* b6, const void* b7, const void* b8,
                         const void* b9, const uint32_t* __restrict__ flag,
                         uint16_t* __restrict__ Wp9, float* __restrict__ bpk,
                         float* __restrict__ b9pk) {
  const bool isbf = flag[0] != 0;
  int m = blockIdx.y;
  int k = blockIdx.x * 256 + threadIdx.x;
  int r = k >> 8, cin = k & 255;
  int dy = r / 3, dx = r - dy * 3;
  Wp9[(size_t)m * 2304 + k] = f2bf(load_in(w9, (size_t)((m * 256 + cin) * 3 + dy) * 3 + dx, isbf));
  if (blockIdx.x == 0 && m < 9) {
    const void* bs[8] = {b1, b2, b3, b4, b5, b6, b7, b8};
    int t = threadIdx.x;
    if (m < 8) {
      int cls = m >> 1, branch = m & 1;
      bpk[m * 256 + t] = load_in(bs[branch * 4 + cls], t, isbf);
    } else {
      b9pk[t] = load_in(b9, t, isbf);
    }
  }
}

// ---------------- pad + NCHW->NHWC for x: LDS transpose + border zero ------
// Block per (b,i): tile 512c x 32j. Read coalesced (float4/uint2 along j),
// transpose via swizzled LDS, write 1KB-contiguous NHWC runs.
// Border zeroing replaces the xp memset: each block zeros cols 0,33 of its
// row; i==0 zeros row 0, i==31 zeros row 33.
__global__ __launch_bounds__(256) void pad_x_kernel(const void* __restrict__ x,
                                                    const uint32_t* __restrict__ flag,
                                                    uint16_t* __restrict__ xp) {
  __shared__ uint16_t lt[512 * 32];  // 32 KiB
  const bool isbf = flag[0] != 0;
  const int t = threadIdx.x;
  const int b = blockIdx.x >> 5, i = blockIdx.x & 31;
  const uint4 zero4 = make_uint4(0u, 0u, 0u, 0u);
  // border zero: own row (i+1) cols 0 and 33 (512 ch each = 64 uint4)
  {
    const size_t row = (size_t)(b * 34 + i + 1) * 34;
    if (t < 64) *(uint4*)&xp[(row + 0) * 512 + t * 8] = zero4;
    else if (t < 128) *(uint4*)&xp[(row + 33) * 512 + (t - 64) * 8] = zero4;
  }
  if (i == 0) {  // full row 0: 34*512 u16 = 2176 uint4
    const size_t r0 = (size_t)(b * 34 + 0) * 34 * 512;
    for (int idx = t; idx < 2176; idx += 256) *(uint4*)&xp[r0 + idx * 8] = zero4;
  }
  if (i == 31) {  // full row 33
    const size_t r33 = (size_t)(b * 34 + 33) * 34 * 512;
    for (int idx = t; idx < 2176; idx += 256) *(uint4*)&xp[r33 + idx * 8] = zero4;
  }
  const int jg = t & 7;
  for (int it = 0; it < 16; ++it) {
    const int c = (t >> 3) + it * 32;
    const size_t src = ((size_t)(b * 512 + c) * 32 + i) * 32 + jg * 4;
    uint16_t v[4];
    if (isbf) {
      uint2 d = *(const uint2*)((const uint16_t*)x + src);
      v[0] = (uint16_t)(d.x & 0xffff); v[1] = (uint16_t)(d.x >> 16);
      v[2] = (uint16_t)(d.y & 0xffff); v[3] = (uint16_t)(d.y >> 16);
    } else {
      float4 d = *(const float4*)((const float*)x + src);
      v[0] = f2bf(d.x); v[1] = f2bf(d.y); v[2] = f2bf(d.z); v[3] = f2bf(d.w);
    }
    const int sw = ((c >> 3) & 15) << 1;
#pragma unroll
    for (int e = 0; e < 4; ++e) lt[c * 32 + ((jg * 4 + e) ^ sw)] = v[e];
  }
  __syncthreads();
  const int cg = t & 63;
  for (int it = 0; it < 8; ++it) {
    const int j = it * 4 + (t >> 6);
    uint16_t v[8];
#pragma unroll
    for (int e = 0; e < 8; ++e) {
      const int R = cg * 8 + e;  // R>>3 == cg
      v[e] = lt[R * 32 + (j ^ ((cg & 15) << 1))];
    }
    *(uint4*)&xp[((size_t)(b * 34 + i + 1) * 34 + (j + 1)) * 512 + cg * 8] = *(const uint4*)v;
  }
}

// ---------------- implicit-GEMM conv body, m97-style, BK=64 ----------------
// MODE 0: unpool classes (class-planar y + bias). MODE 1: conv9 (NCHW 64x64).
// BM=BN=128, 256 threads = 4 waves (2m x 2n), wave tile 64x64.
// LDS per matrix: [2 khalf][128 rows][32 cols] bf16 (16 KiB), single-buffered.
// 16B slots XOR-swizzled with row bits 1-2 (R9-verified, 0 conflicts):
// source col slot^=((lane>>3)&3); read slot = kg ^ ((fl>>1)&3)  (rule 21).
// R17: epilogue also emits per-block BN partial sums (s, s^2 of the rounded
// outputs, reduced over the block's 128-n slice) into P — deterministic,
// no atomics. MODE0 layout: P[(((cls*4+mt)*128+nt)*128+q)*2]; MODE1:
// P[((mt*512+nt)*128+q)*2], q = channel within block.
template <int CIN, int IMGW_SHIFT, int PIXB_SHIFT, int PADW, int MODE>
__device__ __forceinline__ void gemm_conv_body(const uint16_t* __restrict__ Wp,
                                               const uint16_t* __restrict__ xp,
                                               const float* __restrict__ bias,
                                               uint16_t* __restrict__ o0,
                                               uint16_t* __restrict__ o1,
                                               float* __restrict__ P) {
  constexpr int IMGW = 1 << IMGW_SHIFT;
  constexpr int CSH = (CIN == 512) ? 9 : 8;  // k -> tap shift
  __shared__ uint16_t As[2 * 128 * 32];  // 16 KiB
  __shared__ uint16_t Bs[2 * 128 * 32];  // 16 KiB

  const int tid = threadIdx.x;
  const int wave = tid >> 6, lane = tid & 63;

  int cls, mt, nt;
  if (MODE == 0) {
    // class-major (A first, D last = tail filler); within class mt-major so
    // each XCD stripe keeps one (cls,mt) A-panel (1.2 MB) L2-resident.
    const int bid = blockIdx.x;
    cls = bid >> 9;
    const int w = bid & 511;
    mt = w >> 7;
    nt = w & 127;
  } else {
    cls = 0;
    mt = blockIdx.x >> 9;
    nt = blockIdx.x & 511;
  }
  const int n0 = nt * 128;
  const int ntaps = (MODE == 0) ? cls_ntaps(cls) : 9;
  const int Krow = ntaps * CIN;   // packed row stride
  const int NT = Krow >> 6;       // K-tiles of 64
  const int mrow0 = mt * 128;
  const uint16_t* Wbase = (MODE == 0) ? Wp + cls_off(cls) : Wp;

  // staging map per wave-instr (1KB): 16 rows x 32 elems (one k-half chunk);
  // lane -> (row = lane>>2, slot = lane&3); SOURCE col pre-swizzled with
  // row bits 1-2 = (lane>>3)&3 so the linear LDS write lands swizzled data.
  const int srow = lane >> 2;
  const int scol = (((lane & 3) ^ ((lane >> 3) & 3)) << 3);  // elements

  const uint16_t* aS[2];
#pragma unroll
  for (int g = 0; g < 2; ++g)
    aS[g] = Wbase + (size_t)(mrow0 + wave * 32 + g * 16 + srow) * Krow + scol;

  auto pixb = [&](int n) -> size_t {
    const int bb = n >> PIXB_SHIFT;
    const int rem = n & ((1 << PIXB_SHIFT) - 1);
    const int hh = rem >> IMGW_SHIFT;
    const int ww = rem & (IMGW - 1);
    return ((size_t)(bb * PADW + hh) * PADW + ww) * CIN;
  };
  const uint16_t* bS[2];
#pragma unroll
  for (int g = 0; g < 2; ++g)
    bS[g] = xp + pixb(n0 + wave * 32 + g * 16 + srow) + scol;

  uint16_t* aD = &As[wave * 1024];  // wave-uniform LDS staging bases
  uint16_t* bD = &Bs[wave * 1024];

  auto stageA = [&](int kh, int k0) {
#pragma unroll
    for (int g = 0; g < 2; ++g)
      load_lds16(aS[g] + k0 + kh * 32, aD + kh * 4096 + g * 512);
  };
  auto stageB = [&](int kh, size_t bo) {
#pragma unroll
    for (int g = 0; g < 2; ++g)
      load_lds16(bS[g] + bo + kh * 32, bD + kh * 4096 + g * 512);
  };
  auto bofff = [&](int t) -> size_t {
    const int k0 = t << 6;
    const int r = k0 >> CSH;
    int dy, dx;
    if (MODE == 0) cls_tap(cls, r, dy, dx);
    else { dy = r / 3; dx = r - 3 * dy; }
    return (size_t)(dy * PADW + dx) * CIN + (k0 & (CIN - 1));
  };

  floatx4 acc[4][4];
#pragma unroll
  for (int i = 0; i < 4; ++i)
#pragma unroll
    for (int j = 0; j < 4; ++j) acc[i][j] = floatx4{0.f, 0.f, 0.f, 0.f};

  const int wm = wave >> 1, wn = wave & 1;
  const int fl = lane & 15, kg = lane >> 4;
  // read-side swizzle: slot = kg ^ (row bits 1-2) = kg ^ ((fl>>1)&3)
  const int eoff = ((kg ^ ((fl >> 1) & 3)) << 3);
  const int aoff = (wm * 64 + fl) * 32 + eoff;  // frag base in k-half plane
  const int boff_r = (wn * 64 + fl) * 32 + eoff;

  for (int t = 0; t < NT; ++t) {
    const int k0 = t << 6;
    const size_t bo = bofff(t);
    stageA(0, k0); stageB(0, bo);
    stageA(1, k0); stageB(1, bo);
    __syncthreads();  // compiler emits vmcnt(0) drain before barrier
#pragma unroll
    for (int kh = 0; kh < 2; ++kh) {
      bf16x8 af[4], bfr[4];
#pragma unroll
      for (int i = 0; i < 4; ++i) af[i] = *(const bf16x8*)&As[kh * 4096 + aoff + i * 512];
#pragma unroll
      for (int j = 0; j < 4; ++j) bfr[j] = *(const bf16x8*)&Bs[kh * 4096 + boff_r + j * 512];
      __builtin_amdgcn_s_setprio(1);
#pragma unroll
      for (int i = 0; i < 4; ++i)
#pragma unroll
        for (int j = 0; j < 4; ++j)
          acc[i][j] = __builtin_amdgcn_mfma_f32_16x16x32_bf16(af[i], bfr[j], acc[i][j], 0, 0, 0);
      __builtin_amdgcn_s_setprio(0);
    }
    __syncthreads();  // protect LDS from next tile's stage
  }

  // epilogue: C/D layout col=lane&15 (n), row=(lane>>4)*4+reg (m)  [m89]
  // MODE 0 stores class-planar y[cls][b][cout][32][32] -> coalesced 32B runs.
  // Fused BN partials: s/s2 of rounded outputs, shfl-reduce over the 16-lane
  // n-group, LDS combine across the 2 n-half waves (As reused post-loop).
  float* Lf = (float*)As;
#pragma unroll
  for (int i = 0; i < 4; ++i) {
#pragma unroll
    for (int reg = 0; reg < 4; ++reg) {
      const int mloc = mrow0 + wm * 64 + i * 16 + kg * 4 + reg;
      float s = 0.f, s2 = 0.f;
      if (MODE == 0) {
        const int branch = mloc >> 8, cout = mloc & 255;
        const float bv = bias[cls * 512 + mloc];
        uint16_t* o = branch ? o1 : o0;
#pragma unroll
        for (int j4 = 0; j4 < 4; ++j4) {
          const int n = n0 + wn * 64 + j4 * 16 + fl;
          const uint16_t hb = f2bf(acc[i][j4][reg] + bv);
          const float v = bf2f(hb);
          s += v; s2 += v * v;
          const int bb = n >> 10, hh = (n >> 5) & 31, ww = n & 31;
          o[((size_t)((cls * 16 + bb) * 256 + cout) << 10) + (hh << 5) + ww] = hb;
        }
      } else {
        const float bv = bias[mloc];
#pragma unroll
        for (int j4 = 0; j4 < 4; ++j4) {
          const int n = n0 + wn * 64 + j4 * 16 + fl;
          const uint16_t hb = f2bf(acc[i][j4][reg] + bv);
          const float v = bf2f(hb);
          s += v; s2 += v * v;
          const int bb = n >> 12, hh = (n >> 6) & 63, ww = n & 63;
          o0[((size_t)((bb * 256 + mloc) * 64 + hh) << 6) + ww] = hb;
        }
      }
#pragma unroll
      for (int off = 1; off < 16; off <<= 1) {
        s += __shfl_xor(s, off);
        s2 += __shfl_xor(s2, off);
      }
      if (fl == 0) {
        const int q = wm * 64 + i * 16 + kg * 4 + reg;
        Lf[(q * 2 + wn) * 2 + 0] = s;
        Lf[(q * 2 + wn) * 2 + 1] = s2;
      }
    }
  }
  __syncthreads();
  if (tid < 128) {
    const float s = Lf[(tid * 2 + 0) * 2 + 0] + Lf[(tid * 2 + 1) * 2 + 0];
    const float s2 = Lf[(tid * 2 + 0) * 2 + 1] + Lf[(tid * 2 + 1) * 2 + 1];
    size_t pi;
    if (MODE == 0) pi = (((size_t)(cls * 4 + mt) * 128 + nt) * 128 + tid) * 2;
    else pi = (((size_t)mt * 512 + nt) * 128 + tid) * 2;
    P[pi] = s;
    P[pi + 1] = s2;
  }
}

// Distinct symbols so rocprof attributes the two GEMMs separately.
// (256,4): (256,5) spills the accumulator (VGPR 60->48, WRITE x13).
__global__ __launch_bounds__(256, 4) void gemm_unpool(const uint16_t* __restrict__ Wp,
                                                      const uint16_t* __restrict__ xp,
                                                      const float* __restrict__ bias,
                                                      uint16_t* __restrict__ o0,
                                                      uint16_t* __restrict__ o1,
                                                      float* __restrict__ P) {
  gemm_conv_body<512, 5, 10, 34, 0>(Wp, xp, bias, o0, o1, P);
}
__global__ __launch_bounds__(256, 4) void gemm_conv9(const uint16_t* __restrict__ Wp,
                                                     const uint16_t* __restrict__ xp,
                                                     const float* __restrict__ bias,
                                                     uint16_t* __restrict__ o0,
                                                     uint16_t* __restrict__ o1,
                                                     float* __restrict__ P) {
  gemm_conv_body<256, 6, 12, 66, 1>(Wp, xp, bias, o0, o1, P);
}

// ---------------- BN finalize (partials -> scale/shift) ----------------
// unpool: grid 2 (branch). thread c: channel mloc = branch*256+c; sum over
// 4 cls x 128 nt partial records. 65536 elements per channel.
__global__ void bn_fin_unpool(const float* __restrict__ P,
                              const void* __restrict__ g1, const void* __restrict__ be1,
                              const void* __restrict__ g2, const void* __restrict__ be2,
                              const uint32_t* __restrict__ flag,
                              float2* __restrict__ o1, float2* __restrict__ o2) {
  const bool isbf = flag[0] != 0;
  const int branch = blockIdx.x, c = threadIdx.x;
  const int mloc = branch * 256 + c, mt = mloc >> 7, q = mloc & 127;
  float s = 0.f, s2 = 0.f;
  for (int cls = 0; cls < 4; ++cls)
    for (int nt = 0; nt < 128; ++nt) {
      const float2 p = *(const float2*)&P[(((size_t)(cls * 4 + mt) * 128 + nt) * 128 + q) * 2];
      s += p.x; s2 += p.y;
    }
  const float mean = s * (1.f / 65536.f);
  const float var = s2 * (1.f / 65536.f) - mean * mean;
  const void* gm = branch ? g2 : g1;
  const void* bt = branch ? be2 : be1;
  const float scale = load_in(gm, c, isbf) * rsqrtf(var + 1e-5f);
  const float shift = load_in(bt, c, isbf) - mean * scale;
  (branch ? o2 : o1)[c] = make_float2(scale, shift);
}

// conv9: 1 block. thread c: channel c; mt = c>>7 selects the block row;
// 512 nt records. 65536 elements per channel.
__global__ void bn_fin_conv9(const float* __restrict__ P,
                             const void* __restrict__ gamma, const void* __restrict__ beta,
                             const uint32_t* __restrict__ flag, float2* __restrict__ out) {
  const bool isbf = flag[0] != 0;
  const int c = threadIdx.x, mt = c >> 7, q = c & 127;
  float s = 0.f, s2 = 0.f;
  for (int nt = 0; nt < 512; ++nt) {
    const float2 p = *(const float2*)&P[(((size_t)mt * 512 + nt) * 128 + q) * 2];
    s += p.x; s2 += p.y;
  }
  const float mean = s * (1.f / 65536.f);
  const float var = s2 * (1.f / 65536.f) - mean * mean;
  const float scale = load_in(gamma, c, isbf) * rsqrtf(var + 1e-5f);
  const float shift = load_in(beta, c, isbf) - mean * scale;
  out[c] = make_float2(scale, shift);
}

// ------- BN1 + ReLU + planar-y1 -> NHWC pad for conv9 input: LDS transpose --
// Block per (b,h). Border zeroing replaces the u memset: each block zeros
// cols 0,65 of its row; h==0 zeros row 0, h==63 zeros row 65.
__global__ __launch_bounds__(256) void u_fill(const uint16_t* __restrict__ y1,
                                              const float2* __restrict__ st,
                                              uint16_t* __restrict__ u) {
  __shared__ uint16_t lt[512 * 32];  // 32 KiB
  const int t = threadIdx.x;
  const int b = blockIdx.x >> 6, h = blockIdx.x & 63;
  const uint4 zero4 = make_uint4(0u, 0u, 0u, 0u);
  {
    const size_t row = (size_t)(b * 66 + h + 1) * 66;
    if (t < 32) *(uint4*)&u[(row + 0) * 256 + t * 8] = zero4;
    else if (t < 64) *(uint4*)&u[(row + 65) * 256 + (t - 32) * 8] = zero4;
  }
  if (h == 0) {  // full row 0: 66*256 u16 = 2112 uint4
    const size_t r0 = (size_t)(b * 66 + 0) * 66 * 256;
    for (int idx = t; idx < 2112; idx += 256) *(uint4*)&u[r0 + idx * 8] = zero4;
  }
  if (h == 63) {  // full row 65
    const size_t r65 = (size_t)(b * 66 + 65) * 66 * 256;
    for (int idx = t; idx < 2112; idx += 256) *(uint4*)&u[r65 + idx * 8] = zero4;
  }
  const int clsE = h & 1, h2 = h >> 1;
  const int wg = t & 7;
  for (int it = 0; it < 16; ++it) {
    const int R = (t >> 3) + it * 32;  // p*256 + c
    const int p = R >> 8, c = R & 255;
    const int cls = clsE + 2 * p;
    const float2 ab = st[c];
    const size_t src = ((size_t)((cls * 16 + b) * 256 + c) << 10) + (h2 << 5) + wg * 4;
    uint2 d = *(const uint2*)&y1[src];
    uint16_t v[4];
    v[0] = f2bf(fmaxf(ab.x * bf2f(d.x & 0xffff) + ab.y, 0.f));
    v[1] = f2bf(fmaxf(ab.x * bf2f(d.x >> 16) + ab.y, 0.f));
    v[2] = f2bf(fmaxf(ab.x * bf2f(d.y & 0xffff) + ab.y, 0.f));
    v[3] = f2bf(fmaxf(ab.x * bf2f(d.y >> 16) + ab.y, 0.f));
    const int sw = ((R >> 3) & 15) << 1;
#pragma unroll
    for (int e = 0; e < 4; ++e) lt[R * 32 + ((wg * 4 + e) ^ sw)] = v[e];
  }
  __syncthreads();
  const int cg = t & 31;
  for (int it = 0; it < 8; ++it) {
    const int w = it * 8 + (t >> 5);
    const int p = w & 1, w2 = w >> 1;
    uint16_t v[8];
#pragma unroll
    for (int e = 0; e < 8; ++e) {
      const int R = p * 256 + cg * 8 + e;
      v[e] = lt[R * 32 + (w2 ^ (((R >> 3) & 15) << 1))];
    }
    *(uint4*)&u[((size_t)(b * 66 + h + 1) * 66 + (w + 1)) * 256 + cg * 8] = *(const uint4*)v;
  }
}

// ---------------- final: relu(BN2(z) + BN12(y2)) -> out (dtype per flag) ----
// z is NCHW 64x64; y2 is class-planar.
__global__ void final_kernel(const uint16_t* __restrict__ z, const uint16_t* __restrict__ y2,
                             const float2* __restrict__ st2, const float2* __restrict__ st12,
                             const uint32_t* __restrict__ flag, void* __restrict__ out) {
  const bool isbf = flag[0] != 0;
  size_t idx = ((size_t)blockIdx.x * 256 + threadIdx.x) * 8;
  const int b = (int)(idx >> 20), c = (int)((idx >> 12) & 255);
  const int H = (int)((idx >> 6) & 63), W0 = (int)(idx & 63);
  float2 a2 = st2[c], a12 = st12[c];
  const int clsE = H & 1;  // W even -> ex=0
  const size_t pE = (((size_t)((clsE * 16 + b) * 256 + c)) << 10) + ((H >> 1) << 5) + (W0 >> 1);
  const size_t pO = pE + ((size_t)2 << 22);  // cls+2 plane (ex=1)
  uint2 e2 = *(const uint2*)&y2[pE];
  uint2 o2 = *(const uint2*)&y2[pO];
  uint16_t ye[4] = {(uint16_t)(e2.x & 0xffff), (uint16_t)(e2.x >> 16),
                    (uint16_t)(e2.y & 0xffff), (uint16_t)(e2.y >> 16)};
  uint16_t yo[4] = {(uint16_t)(o2.x & 0xffff), (uint16_t)(o2.x >> 16),
                    (uint16_t)(o2.y & 0xffff), (uint16_t)(o2.y >> 16)};
  uint4 vz = *(const uint4*)(z + idx);
  uint16_t zz[8] = {(uint16_t)(vz.x & 0xffff), (uint16_t)(vz.x >> 16),
                    (uint16_t)(vz.y & 0xffff), (uint16_t)(vz.y >> 16),
                    (uint16_t)(vz.z & 0xffff), (uint16_t)(vz.z >> 16),
                    (uint16_t)(vz.w & 0xffff), (uint16_t)(vz.w >> 16)};
  float r[8];
#pragma unroll
  for (int j = 0; j < 8; ++j) {
    uint16_t yv = (j & 1) ? yo[j >> 1] : ye[j >> 1];
    r[j] = fmaxf(a2.x * bf2f(zz[j]) + a2.y + a12.x * bf2f(yv) + a12.y, 0.f);
  }
  if (isbf) {
    uint4 vo;
    vo.x = (uint32_t)f2bf(r[0]) | ((uint32_t)f2bf(r[1]) << 16);
    vo.y = (uint32_t)f2bf(r[2]) | ((uint32_t)f2bf(r[3]) << 16);
    vo.z = (uint32_t)f2bf(r[4]) | ((uint32_t)f2bf(r[5]) << 16);
    vo.w = (uint32_t)f2bf(r[6]) | ((uint32_t)f2bf(r[7]) << 16);
    *(uint4*)((uint16_t*)out + idx) = vo;
  } else {
    float4* of = (float4*)((float*)out + idx);
    of[0] = make_float4(r[0], r[1], r[2], r[3]);
    of[1] = make_float4(r[4], r[5], r[6], r[7]);
  }
}

// ---------------------------------------------------------------------------
extern "C" void kernel_launch(void* const* d_in, const int* in_sizes, int n_in,
                              void* d_out, int out_size, void* d_ws, size_t ws_size,
                              hipStream_t stream) {
  const void* x = d_in[0];
  const void *w1 = d_in[1], *b1 = d_in[2], *w2 = d_in[3], *b2 = d_in[4];
  const void *w3 = d_in[5], *b3 = d_in[6], *w4 = d_in[7], *b4 = d_in[8];
  const void *w5 = d_in[9], *b5 = d_in[10], *w6 = d_in[11], *b6 = d_in[12];
  const void *w7 = d_in[13], *b7 = d_in[14], *w8 = d_in[15], *b8 = d_in[16];
  const void *w9 = d_in[17], *b9 = d_in[18];
  const void *g11 = d_in[19], *be11 = d_in[20], *g12 = d_in[21], *be12 = d_in[22];
  const void *g2 = d_in[23], *be2 = d_in[24];

  char* ws = (char*)d_ws;
  size_t off = 0;
  auto alloc = [&](size_t bytes) -> char* {
    char* p = ws + off;
    off = (off + bytes + 255) & ~(size_t)255;
    return p;
  };
  const size_t xp_bytes = (size_t)16 * 34 * 34 * 512 * 2;   // 18.94 MB
  const size_t y_bytes = (size_t)16 * 256 * 64 * 64 * 2;    // 33.55 MB (planar: 4*16*256*1024)
  const size_t u_bytes = (size_t)16 * 66 * 66 * 256 * 2;    // 35.68 MB
  const size_t Wp_bytes = (size_t)512 * 12800 * 2;          // 13.11 MB (packed classes)

  uint32_t* flag = (uint32_t*)alloc(256);
  uint16_t* Wp9 = (uint16_t*)alloc((size_t)256 * 2304 * 2);
  float* bpk = (float*)alloc(2048 * 4);
  float* b9pk = (float*)alloc(256 * 4);
  float2* st1a = (float2*)alloc(256 * 8);
  float2* st1b = (float2*)alloc(256 * 8);
  float2* st2 = (float2*)alloc(256 * 8);
  float* P1 = (float*)alloc((size_t)4 * 4 * 128 * 128 * 2 * 4);  // 2 MB BN partials
  float* P9 = P1;  // conv9 partials reuse (P1 dead after bn_fin_unpool)
  uint16_t* y1 = (uint16_t*)alloc(y_bytes);
  uint16_t* y2 = (uint16_t*)alloc(y_bytes);
  // union region: {Wp + xp} (gemm1 inputs) before gemm1; u (conv9 input) after
  size_t wpal = (Wp_bytes + 255) & ~(size_t)255;
  size_t region_bytes = wpal + xp_bytes;
  if (region_bytes < u_bytes) region_bytes = u_bytes;
  char* region = alloc(region_bytes);
  uint16_t* Wp = (uint16_t*)region;
  uint16_t* xp = (uint16_t*)(region + wpal);
  uint16_t* u = (uint16_t*)region;  // overlays Wp+xp, both dead after gemm1
  uint16_t* z = y1;                 // overlays y1, dead after u_fill
  // total footprint ~105 MB

  detect_dtype<<<1, 256, 0, stream>>>((const uint32_t*)x, flag);

  // packed-class weights: one block per m row (coalesced LDS permute)
  pack_w_unpool<<<512, 256, 0, stream>>>(w1, w2, w3, w4, w5, w6, w7, w8, flag, Wp);
  pack_w9b<<<dim3(9, 256), 256, 0, stream>>>(w9, b1, b2, b3, b4, b5, b6, b7, b8, b9,
                                             flag, Wp9, bpk, b9pk);
  // pad_x: one block per (b,i); zeroes xp borders itself (no memset)
  pad_x_kernel<<<512, 256, 0, stream>>>(x, flag, xp);

  // unpool GEMM: 2048 blocks = 4 classes x (4 mt x 128 nt), class-major;
  // also emits BN partial sums into P1
  gemm_unpool<<<2048, 256, 0, stream>>>(Wp, xp, bpk, y1, y2, P1);

  // BN finalize for y1/y2 (replaces the 67MB bn_stats2 re-read)
  bn_fin_unpool<<<2, 256, 0, stream>>>(P1, g11, be11, g12, be12, flag, st1a, st1b);

  // u_fill: one block per (b,h); zeroes u borders itself (no memset)
  u_fill<<<1024, 256, 0, stream>>>(y1, st1a, u);

  // conv9 GEMM: 1024 blocks = 2 mt x 512 nt; z aliases y1 (dead after u_fill)
  gemm_conv9<<<1024, 256, 0, stream>>>(Wp9, u, b9pk, z, nullptr, P9);

  // BN finalize for z (replaces the 33.5MB bn_stats re-read)
  bn_fin_conv9<<<1, 256, 0, stream>>>(P9, g2, be2, flag, st2);

  final_kernel<<<8192, 256, 0, stream>>>(z, y2, st2, st1b, flag, d_out);
}

// Round 15
// 564.078 us; speedup vs baseline: 1.0316x; 1.0316x over previous
//
#include <hip/hip_runtime.h>
#include <stdint.h>

// ---------------------------------------------------------------------------
// UpProj block. Inputs fp32 or bf16 (runtime-detected on device); compute
// bf16 MFMA, fp32 accumulate; output dtype follows input dtype.
//  unpool(4 convs)x2: per conv-CLASS GEMMs packed into one launch.
//    class A (3,3): M=512, K=4608 | B (2,3): K=3072 | C (3,2): K=3072
//    | D (2,2): K=2048   (N=16384)
//  conv9 == GEMM M=256, K=2304, N=65536.
//  R11 (kept): m97-class occupancy GEMM at 906 TF (MfmaUtil 41%, structural
//  ceiling of the 128^2 2-barrier form; 256^2 8-phase ports all regressed).
//  R13 (kept): coalesced LDS-transpose pad_x/u_fill/pack_w.
//  R15/R16 (kept): split gemm symbols, fused border-zero, launch merges,
//  launch_bounds (256,4) (5 blocks/CU spills acc: VGPR 48, WRITE x13).
//  R21: R19's host-side isbf REVERTED (it assumed in_sizes==bytes; absmax
//  7.53 failure -- inputs are fp32 and the guess mis-detected). Device
//  detect_dtype restored (content-based, verified 10+ rounds). KEPT from
//  R19: pad_x + pack_w_unpool + pack_w9b fused into one 3328-block prep
//  launch (index maps re-verified identical). 10 launches -> 8.
// ---------------------------------------------------------------------------

typedef __bf16 bf16x8 __attribute__((ext_vector_type(8)));
typedef float floatx4 __attribute__((ext_vector_type(4)));

typedef __attribute__((address_space(3))) uint32_t lds32_t;
typedef __attribute__((address_space(1))) const uint32_t glb32_t;

__device__ __forceinline__ void load_lds16(const uint16_t* g, uint16_t* l) {
  // async global->LDS: per-lane global addr, LDS dest = wave-uniform base + lane*16B
  __builtin_amdgcn_global_load_lds((glb32_t*)g, (lds32_t*)l, 16, 0, 0);
}

__device__ __forceinline__ float bf2f(uint32_t u) {
  union { uint32_t i; float f; } v;
  v.i = u << 16;
  return v.f;
}
__device__ __forceinline__ uint16_t f2bf(float f) {
  union { float f; uint32_t i; } v;
  v.f = f;
  uint32_t r = v.i + 0x7fff + ((v.i >> 16) & 1);  // RNE
  return (uint16_t)(r >> 16);
}
__device__ __forceinline__ float load_in(const void* p, size_t i, bool isbf) {
  return isbf ? bf2f(((const uint16_t*)p)[i]) : ((const float*)p)[i];
}

// class geometry helpers (cls 0=A,1=B,2=C,3=D; ey=cls&1, ex=cls>>1)
__device__ __forceinline__ int cls_ntaps(int cls) { return cls == 0 ? 9 : (cls == 3 ? 4 : 6); }
__device__ __forceinline__ size_t cls_off(int cls) {
  // element offsets of per-class W blocks: 512*{4608,3072,3072,2048} prefix
  return cls == 0 ? 0u : (cls == 1 ? 2359296u : (cls == 2 ? 3932160u : 5505024u));
}
__device__ __forceinline__ void cls_tap(int cls, int r, int& dy, int& dx) {
  if (cls >= 2) { dy = r >> 1; dx = r & 1; }        // kw=2 classes
  else { dy = r / 3; dx = r - 3 * (r / 3); }        // kw=3 classes
}

// ---------------- dtype detector (device, content-based; verified) --------
__global__ void detect_dtype(const uint32_t* __restrict__ xw, uint32_t* __restrict__ flag) {
  int t = threadIdx.x;
  int cnt = 0;
#pragma unroll
  for (int k = 0; k < 16; ++k) {
    uint32_t u = xw[t + k * 256];
    uint32_t e = (u >> 7) & 0xFF;
    cnt += (e >= 100 && e <= 140) ? 1 : 0;
  }
  __shared__ int rs[256];
  rs[t] = cnt;
  __syncthreads();
  for (int o = 128; o > 0; o >>= 1) {
    if (t < o) rs[t] += rs[t + o];
    __syncthreads();
  }
  if (t == 0) flag[0] = (rs[0] > 2048) ? 1u : 0u;  // 1 = bf16 inputs
}

// ---------------- fused prep: pad_x | pack_w_unpool | pack_w9 + bias -------
// bid [0,512): pad_x block (b,i); [512,1024): pack_w_unpool m=bid-512;
// [1024,3328): pack_w9b q=bid-1024 (m=q/9, kblk=q%9).
__global__ __launch_bounds__(256) void prep(
    const void* __restrict__ x,
    const void* wa, const void* wb, const void* wc, const void* wd,
    const void* we, const void* wf, const void* wg, const void* wh,
    const void* __restrict__ w9,
    const void* b1, const void* b2, const void* b3, const void* b4,
    const void* b5, const void* b6, const void* b7, const void* b8,
    const void* b9, const uint32_t* __restrict__ flag,
    uint16_t* __restrict__ xp, uint16_t* __restrict__ Wp,
    uint16_t* __restrict__ Wp9, float* __restrict__ bpk,
    float* __restrict__ b9pk) {
  __shared__ uint16_t sm[512 * 32];  // 32 KiB union (lt / wl)
  const bool isbf = flag[0] != 0;
  const int t = threadIdx.x;
  const int bid = blockIdx.x;

  if (bid < 512) {
    // ---- pad_x: block (b,i); LDS transpose + border zero ----
    const int b = bid >> 5, i = bid & 31;
    const uint4 zero4 = make_uint4(0u, 0u, 0u, 0u);
    {
      const size_t row = (size_t)(b * 34 + i + 1) * 34;
      if (t < 64) *(uint4*)&xp[(row + 0) * 512 + t * 8] = zero4;
      else if (t < 128) *(uint4*)&xp[(row + 33) * 512 + (t - 64) * 8] = zero4;
    }
    if (i == 0) {
      const size_t r0 = (size_t)(b * 34 + 0) * 34 * 512;
      for (int idx = t; idx < 2176; idx += 256) *(uint4*)&xp[r0 + idx * 8] = zero4;
    }
    if (i == 31) {
      const size_t r33 = (size_t)(b * 34 + 33) * 34 * 512;
      for (int idx = t; idx < 2176; idx += 256) *(uint4*)&xp[r33 + idx * 8] = zero4;
    }
    const int jg = t & 7;
    for (int it = 0; it < 16; ++it) {
      const int c = (t >> 3) + it * 32;
      const size_t src = ((size_t)(b * 512 + c) * 32 + i) * 32 + jg * 4;
      uint16_t v[4];
      if (isbf) {
        uint2 d = *(const uint2*)((const uint16_t*)x + src);
        v[0] = (uint16_t)(d.x & 0xffff); v[1] = (uint16_t)(d.x >> 16);
        v[2] = (uint16_t)(d.y & 0xffff); v[3] = (uint16_t)(d.y >> 16);
      } else {
        float4 d = *(const float4*)((const float*)x + src);
        v[0] = f2bf(d.x); v[1] = f2bf(d.y); v[2] = f2bf(d.z); v[3] = f2bf(d.w);
      }
      const int sw = ((c >> 3) & 15) << 1;
#pragma unroll
      for (int e = 0; e < 4; ++e) sm[c * 32 + ((jg * 4 + e) ^ sw)] = v[e];
    }
    __syncthreads();
    const int cg = t & 63;
    for (int it = 0; it < 8; ++it) {
      const int j = it * 4 + (t >> 6);
      uint16_t v[8];
#pragma unroll
      for (int e = 0; e < 8; ++e) {
        const int R = cg * 8 + e;  // R>>3 == cg
        v[e] = sm[R * 32 + (j ^ ((cg & 15) << 1))];
      }
      *(uint4*)&xp[((size_t)(b * 34 + i + 1) * 34 + (j + 1)) * 512 + cg * 8] = *(const uint4*)v;
    }
  } else if (bid < 1024) {
    // ---- pack_w_unpool: one block per m; coalesced LDS permute ----
    const void* ws[8] = {wa, wb, wc, wd, we, wf, wg, wh};
    const int m = bid - 512;
    const int branch = m >> 8, cout = m & 255;
    int base = 0;
#pragma unroll
    for (int cls = 0; cls < 4; ++cls) {
      const int ntap = cls_ntaps(cls);
      const int cnt = 512 * ntap;
      const void* src = ws[branch * 4 + cls];
      const size_t s0 = (size_t)cout * cnt;
      for (int idx = t; idx < cnt; idx += 256)
        sm[base + idx] = f2bf(load_in(src, s0 + idx, isbf));
      base += cnt;
    }
    __syncthreads();
    for (int kc = t; kc < 12800; kc += 256) {
      int cls, kk, b2_, ntap;
      if (kc < 4608) { cls = 0; kk = kc; b2_ = 0; ntap = 9; }
      else if (kc < 7680) { cls = 1; kk = kc - 4608; b2_ = 4608; ntap = 6; }
      else if (kc < 10752) { cls = 2; kk = kc - 7680; b2_ = 7680; ntap = 6; }
      else { cls = 3; kk = kc - 10752; b2_ = 10752; ntap = 4; }
      const int r = kk >> 9, cin = kk & 511;
      const int Kcls = ntap << 9;
      Wp[cls_off(cls) + (size_t)m * Kcls + kk] = sm[b2_ + cin * ntap + r];
    }
  } else {
    // ---- pack_w9 + bias: q = bid-1024; m = q/9, kblk = q%9 ----
    const int q = bid - 1024;
    const int m = q / 9, kblk = q - m * 9;
    const int k = kblk * 256 + t;
    const int r = k >> 8, cin = k & 255;
    const int dy = r / 3, dx = r - dy * 3;
    Wp9[(size_t)m * 2304 + k] =
        f2bf(load_in(w9, (size_t)((m * 256 + cin) * 3 + dy) * 3 + dx, isbf));
    if (kblk == 0 && m < 9) {
      const void* bs[8] = {b1, b2, b3, b4, b5, b6, b7, b8};
      if (m < 8) {
        const int cls = m >> 1, branch = m & 1;
        bpk[m * 256 + t] = load_in(bs[branch * 4 + cls], t, isbf);
      } else {
        b9pk[t] = load_in(b9, t, isbf);
      }
    }
  }
}

// ---------------- implicit-GEMM conv body, m97-style, BK=64 ----------------
// MODE 0: unpool classes (class-planar y + bias). MODE 1: conv9 (NCHW 64x64).
// BM=BN=128, 256 threads = 4 waves (2m x 2n), wave tile 64x64.
// LDS per matrix: [2 khalf][128 rows][32 cols] bf16 (16 KiB), single-buffered.
// 16B slots XOR-swizzled with row bits 1-2 (R9-verified, 0 conflicts):
// source col slot^=((lane>>3)&3); read slot = kg ^ ((fl>>1)&3)  (rule 21).
template <int CIN, int IMGW_SHIFT, int PIXB_SHIFT, int PADW, int MODE>
__device__ __forceinline__ void gemm_conv_body(const uint16_t* __restrict__ Wp,
                                               const uint16_t* __restrict__ xp,
                                               const float* __restrict__ bias,
                                               uint16_t* __restrict__ o0,
                                               uint16_t* __restrict__ o1) {
  constexpr int IMGW = 1 << IMGW_SHIFT;
  constexpr int CSH = (CIN == 512) ? 9 : 8;  // k -> tap shift
  __shared__ uint16_t As[2 * 128 * 32];  // 16 KiB
  __shared__ uint16_t Bs[2 * 128 * 32];  // 16 KiB

  const int tid = threadIdx.x;
  const int wave = tid >> 6, lane = tid & 63;

  int cls, mt, nt;
  if (MODE == 0) {
    // class-major (A first, D last = tail filler); within class mt-major so
    // each XCD stripe keeps one (cls,mt) A-panel (1.2 MB) L2-resident.
    const int bid = blockIdx.x;
    cls = bid >> 9;
    const int w = bid & 511;
    mt = w >> 7;
    nt = w & 127;
  } else {
    cls = 0;
    mt = blockIdx.x >> 9;
    nt = blockIdx.x & 511;
  }
  const int n0 = nt * 128;
  const int ntaps = (MODE == 0) ? cls_ntaps(cls) : 9;
  const int Krow = ntaps * CIN;   // packed row stride
  const int NT = Krow >> 6;       // K-tiles of 64
  const int mrow0 = mt * 128;
  const uint16_t* Wbase = (MODE == 0) ? Wp + cls_off(cls) : Wp;

  // staging map per wave-instr (1KB): 16 rows x 32 elems (one k-half chunk);
  // lane -> (row = lane>>2, slot = lane&3); SOURCE col pre-swizzled with
  // row bits 1-2 = (lane>>3)&3 so the linear LDS write lands swizzled data.
  const int srow = lane >> 2;
  const int scol = (((lane & 3) ^ ((lane >> 3) & 3)) << 3);  // elements

  const uint16_t* aS[2];
#pragma unroll
  for (int g = 0; g < 2; ++g)
    aS[g] = Wbase + (size_t)(mrow0 + wave * 32 + g * 16 + srow) * Krow + scol;

  auto pixb = [&](int n) -> size_t {
    const int bb = n >> PIXB_SHIFT;
    const int rem = n & ((1 << PIXB_SHIFT) - 1);
    const int hh = rem >> IMGW_SHIFT;
    const int ww = rem & (IMGW - 1);
    return ((size_t)(bb * PADW + hh) * PADW + ww) * CIN;
  };
  const uint16_t* bS[2];
#pragma unroll
  for (int g = 0; g < 2; ++g)
    bS[g] = xp + pixb(n0 + wave * 32 + g * 16 + srow) + scol;

  uint16_t* aD = &As[wave * 1024];  // wave-uniform LDS staging bases
  uint16_t* bD = &Bs[wave * 1024];

  auto stageA = [&](int kh, int k0) {
#pragma unroll
    for (int g = 0; g < 2; ++g)
      load_lds16(aS[g] + k0 + kh * 32, aD + kh * 4096 + g * 512);
  };
  auto stageB = [&](int kh, size_t bo) {
#pragma unroll
    for (int g = 0; g < 2; ++g)
      load_lds16(bS[g] + bo + kh * 32, bD + kh * 4096 + g * 512);
  };
  auto bofff = [&](int t) -> size_t {
    const int k0 = t << 6;
    const int r = k0 >> CSH;
    int dy, dx;
    if (MODE == 0) cls_tap(cls, r, dy, dx);
    else { dy = r / 3; dx = r - 3 * dy; }
    return (size_t)(dy * PADW + dx) * CIN + (k0 & (CIN - 1));
  };

  floatx4 acc[4][4];
#pragma unroll
  for (int i = 0; i < 4; ++i)
#pragma unroll
    for (int j = 0; j < 4; ++j) acc[i][j] = floatx4{0.f, 0.f, 0.f, 0.f};

  const int wm = wave >> 1, wn = wave & 1;
  const int fl = lane & 15, kg = lane >> 4;
  // read-side swizzle: slot = kg ^ (row bits 1-2) = kg ^ ((fl>>1)&3)
  const int eoff = ((kg ^ ((fl >> 1) & 3)) << 3);
  const int aoff = (wm * 64 + fl) * 32 + eoff;  // frag base in k-half plane
  const int boff_r = (wn * 64 + fl) * 32 + eoff;

  for (int t = 0; t < NT; ++t) {
    const int k0 = t << 6;
    const size_t bo = bofff(t);
    stageA(0, k0); stageB(0, bo);
    stageA(1, k0); stageB(1, bo);
    __syncthreads();  // compiler emits vmcnt(0) drain before barrier
#pragma unroll
    for (int kh = 0; kh < 2; ++kh) {
      bf16x8 af[4], bfr[4];
#pragma unroll
      for (int i = 0; i < 4; ++i) af[i] = *(const bf16x8*)&As[kh * 4096 + aoff + i * 512];
#pragma unroll
      for (int j = 0; j < 4; ++j) bfr[j] = *(const bf16x8*)&Bs[kh * 4096 + boff_r + j * 512];
      __builtin_amdgcn_s_setprio(1);
#pragma unroll
      for (int i = 0; i < 4; ++i)
#pragma unroll
        for (int j = 0; j < 4; ++j)
          acc[i][j] = __builtin_amdgcn_mfma_f32_16x16x32_bf16(af[i], bfr[j], acc[i][j], 0, 0, 0);
      __builtin_amdgcn_s_setprio(0);
    }
    __syncthreads();  // protect LDS from next tile's stage
  }

  // epilogue: C/D layout col=lane&15 (n), row=(lane>>4)*4+reg (m)  [m89]
  // MODE 0 stores class-planar y[cls][b][cout][32][32] -> coalesced 32B runs.
#pragma unroll
  for (int i = 0; i < 4; ++i) {
#pragma unroll
    for (int reg = 0; reg < 4; ++reg) {
      const int mloc = mrow0 + wm * 64 + i * 16 + kg * 4 + reg;
      if (MODE == 0) {
        const int branch = mloc >> 8, cout = mloc & 255;
        const float bv = bias[cls * 512 + mloc];
        uint16_t* o = branch ? o1 : o0;
#pragma unroll
        for (int j4 = 0; j4 < 4; ++j4) {
          const int n = n0 + wn * 64 + j4 * 16 + fl;
          const int bb = n >> 10, hh = (n >> 5) & 31, ww = n & 31;
          o[((size_t)((cls * 16 + bb) * 256 + cout) << 10) + (hh << 5) + ww] =
              f2bf(acc[i][j4][reg] + bv);
        }
      } else {
        const float bv = bias[mloc];
#pragma unroll
        for (int j4 = 0; j4 < 4; ++j4) {
          const int n = n0 + wn * 64 + j4 * 16 + fl;
          const int bb = n >> 12, hh = (n >> 6) & 63, ww = n & 63;
          o0[((size_t)((bb * 256 + mloc) * 64 + hh) << 6) + ww] = f2bf(acc[i][j4][reg] + bv);
        }
      }
    }
  }
}

// Distinct symbols so rocprof attributes the two GEMMs separately.
// (256,4): (256,5) spills the accumulator (VGPR 60->48, WRITE x13).
__global__ __launch_bounds__(256, 4) void gemm_unpool(const uint16_t* __restrict__ Wp,
                                                      const uint16_t* __restrict__ xp,
                                                      const float* __restrict__ bias,
                                                      uint16_t* __restrict__ o0,
                                                      uint16_t* __restrict__ o1) {
  gemm_conv_body<512, 5, 10, 34, 0>(Wp, xp, bias, o0, o1);
}
__global__ __launch_bounds__(256, 4) void gemm_conv9(const uint16_t* __restrict__ Wp,
                                                     const uint16_t* __restrict__ xp,
                                                     const float* __restrict__ bias,
                                                     uint16_t* __restrict__ o0,
                                                     uint16_t* __restrict__ o1) {
  gemm_conv_body<256, 6, 12, 66, 1>(Wp, xp, bias, o0, o1);
}

// ---------------- BN stats ----------------
// Pair version: y1 and y2 (planar, R=512) in one launch; sel = bid>>8.
__global__ void bn_stats2(const uint16_t* __restrict__ y1, const uint16_t* __restrict__ y2,
                          const void* __restrict__ g1, const void* __restrict__ be1,
                          const void* __restrict__ g2, const void* __restrict__ be2,
                          const uint32_t* __restrict__ flag,
                          float2* __restrict__ o1, float2* __restrict__ o2) {
  const bool isbf = flag[0] != 0;
  const int sel = blockIdx.x >> 8;
  const int c = blockIdx.x & 255, t = threadIdx.x;
  const uint32_t* yu = (const uint32_t*)(sel ? y2 : y1);
  float s = 0.f, s2 = 0.f;
  for (int r = 0; r < 64; ++r) {
    size_t base = (size_t)(r * 256 + c) * 512;
#pragma unroll
    for (int k = 0; k < 2; ++k) {
      uint32_t v = yu[base + t + k * 256];
      float lo = bf2f(v & 0xffff), hi = bf2f(v >> 16);
      s += lo + hi;
      s2 += lo * lo + hi * hi;
    }
  }
  __shared__ float rs[256], rs2[256];
  rs[t] = s; rs2[t] = s2;
  __syncthreads();
  for (int off = 128; off > 0; off >>= 1) {
    if (t < off) { rs[t] += rs[t + off]; rs2[t] += rs2[t + off]; }
    __syncthreads();
  }
  if (t == 0) {
    float mean = rs[0] * (1.f / 65536.f);
    float var = rs2[0] * (1.f / 65536.f) - mean * mean;
    const void* gm = sel ? g2 : g1;
    const void* bt = sel ? be2 : be1;
    float scale = load_in(gm, c, isbf) * rsqrtf(var + 1e-5f);
    float shift = load_in(bt, c, isbf) - mean * scale;
    (sel ? o2 : o1)[c] = make_float2(scale, shift);
  }
}

// Single version for z (NCHW64, R=2048).
__global__ void bn_stats(const uint16_t* __restrict__ y, const void* __restrict__ gamma,
                         const void* __restrict__ beta, const uint32_t* __restrict__ flag,
                         float2* __restrict__ out, int R) {
  const bool isbf = flag[0] != 0;
  int c = blockIdx.x, t = threadIdx.x;
  const uint32_t* yu = (const uint32_t*)y;
  const int rows = 32768 / R, kw = R / 256;
  float s = 0.f, s2 = 0.f;
  for (int r = 0; r < rows; ++r) {
    size_t base = (size_t)(r * 256 + c) * R;
    for (int k = 0; k < kw; ++k) {
      uint32_t v = yu[base + t + k * 256];
      float lo = bf2f(v & 0xffff), hi = bf2f(v >> 16);
      s += lo + hi;
      s2 += lo * lo + hi * hi;
    }
  }
  __shared__ float rs[256], rs2[256];
  rs[t] = s; rs2[t] = s2;
  __syncthreads();
  for (int off = 128; off > 0; off >>= 1) {
    if (t < off) { rs[t] += rs[t + off]; rs2[t] += rs2[t + off]; }
    __syncthreads();
  }
  if (t == 0) {
    float mean = rs[0] * (1.f / 65536.f);
    float var = rs2[0] * (1.f / 65536.f) - mean * mean;
    float scale = load_in(gamma, c, isbf) * rsqrtf(var + 1e-5f);
    float shift = load_in(beta, c, isbf) - mean * scale;
    out[c] = make_float2(scale, shift);
  }
}

// ------- BN1 + ReLU + planar-y1 -> NHWC pad for conv9 input: LDS transpose --
// Block per (b,h). Border zeroing replaces the u memset: each block zeros
// cols 0,65 of its row; h==0 zeros row 0, h==63 zeros row 65.
__global__ __launch_bounds__(256) void u_fill(const uint16_t* __restrict__ y1,
                                              const float2* __restrict__ st,
                                              uint16_t* __restrict__ u) {
  __shared__ uint16_t lt[512 * 32];  // 32 KiB
  const int t = threadIdx.x;
  const int b = blockIdx.x >> 6, h = blockIdx.x & 63;
  const uint4 zero4 = make_uint4(0u, 0u, 0u, 0u);
  {
    const size_t row = (size_t)(b * 66 + h + 1) * 66;
    if (t < 32) *(uint4*)&u[(row + 0) * 256 + t * 8] = zero4;
    else if (t < 64) *(uint4*)&u[(row + 65) * 256 + (t - 32) * 8] = zero4;
  }
  if (h == 0) {  // full row 0: 66*256 u16 = 2112 uint4
    const size_t r0 = (size_t)(b * 66 + 0) * 66 * 256;
    for (int idx = t; idx < 2112; idx += 256) *(uint4*)&u[r0 + idx * 8] = zero4;
  }
  if (h == 63) {  // full row 65
    const size_t r65 = (size_t)(b * 66 + 65) * 66 * 256;
    for (int idx = t; idx < 2112; idx += 256) *(uint4*)&u[r65 + idx * 8] = zero4;
  }
  const int clsE = h & 1, h2 = h >> 1;
  const int wg = t & 7;
  for (int it = 0; it < 16; ++it) {
    const int R = (t >> 3) + it * 32;  // p*256 + c
    const int p = R >> 8, c = R & 255;
    const int cls = clsE + 2 * p;
    const float2 ab = st[c];
    const size_t src = ((size_t)((cls * 16 + b) * 256 + c) << 10) + (h2 << 5) + wg * 4;
    uint2 d = *(const uint2*)&y1[src];
    uint16_t v[4];
    v[0] = f2bf(fmaxf(ab.x * bf2f(d.x & 0xffff) + ab.y, 0.f));
    v[1] = f2bf(fmaxf(ab.x * bf2f(d.x >> 16) + ab.y, 0.f));
    v[2] = f2bf(fmaxf(ab.x * bf2f(d.y & 0xffff) + ab.y, 0.f));
    v[3] = f2bf(fmaxf(ab.x * bf2f(d.y >> 16) + ab.y, 0.f));
    const int sw = ((R >> 3) & 15) << 1;
#pragma unroll
    for (int e = 0; e < 4; ++e) lt[R * 32 + ((wg * 4 + e) ^ sw)] = v[e];
  }
  __syncthreads();
  const int cg = t & 31;
  for (int it = 0; it < 8; ++it) {
    const int w = it * 8 + (t >> 5);
    const int p = w & 1, w2 = w >> 1;
    uint16_t v[8];
#pragma unroll
    for (int e = 0; e < 8; ++e) {
      const int R = p * 256 + cg * 8 + e;
      v[e] = lt[R * 32 + (w2 ^ (((R >> 3) & 15) << 1))];
    }
    *(uint4*)&u[((size_t)(b * 66 + h + 1) * 66 + (w + 1)) * 256 + cg * 8] = *(const uint4*)v;
  }
}

// ---------------- final: relu(BN2(z) + BN12(y2)) -> out (dtype per flag) ----
// z is NCHW 64x64; y2 is class-planar.
__global__ void final_kernel(const uint16_t* __restrict__ z, const uint16_t* __restrict__ y2,
                             const float2* __restrict__ st2, const float2* __restrict__ st12,
                             const uint32_t* __restrict__ flag, void* __restrict__ out) {
  const bool isbf = flag[0] != 0;
  size_t idx = ((size_t)blockIdx.x * 256 + threadIdx.x) * 8;
  const int b = (int)(idx >> 20), c = (int)((idx >> 12) & 255);
  const int H = (int)((idx >> 6) & 63), W0 = (int)(idx & 63);
  float2 a2 = st2[c], a12 = st12[c];
  const int clsE = H & 1;  // W even -> ex=0
  const size_t pE = (((size_t)((clsE * 16 + b) * 256 + c)) << 10) + ((H >> 1) << 5) + (W0 >> 1);
  const size_t pO = pE + ((size_t)2 << 22);  // cls+2 plane (ex=1)
  uint2 e2 = *(const uint2*)&y2[pE];
  uint2 o2 = *(const uint2*)&y2[pO];
  uint16_t ye[4] = {(uint16_t)(e2.x & 0xffff), (uint16_t)(e2.x >> 16),
                    (uint16_t)(e2.y & 0xffff), (uint16_t)(e2.y >> 16)};
  uint16_t yo[4] = {(uint16_t)(o2.x & 0xffff), (uint16_t)(o2.x >> 16),
                    (uint16_t)(o2.y & 0xffff), (uint16_t)(o2.y >> 16)};
  uint4 vz = *(const uint4*)(z + idx);
  uint16_t zz[8] = {(uint16_t)(vz.x & 0xffff), (uint16_t)(vz.x >> 16),
                    (uint16_t)(vz.y & 0xffff), (uint16_t)(vz.y >> 16),
                    (uint16_t)(vz.z & 0xffff), (uint16_t)(vz.z >> 16),
                    (uint16_t)(vz.w & 0xffff), (uint16_t)(vz.w >> 16)};
  float r[8];
#pragma unroll
  for (int j = 0; j < 8; ++j) {
    uint16_t yv = (j & 1) ? yo[j >> 1] : ye[j >> 1];
    r[j] = fmaxf(a2.x * bf2f(zz[j]) + a2.y + a12.x * bf2f(yv) + a12.y, 0.f);
  }
  if (isbf) {
    uint4 vo;
    vo.x = (uint32_t)f2bf(r[0]) | ((uint32_t)f2bf(r[1]) << 16);
    vo.y = (uint32_t)f2bf(r[2]) | ((uint32_t)f2bf(r[3]) << 16);
    vo.z = (uint32_t)f2bf(r[4]) | ((uint32_t)f2bf(r[5]) << 16);
    vo.w = (uint32_t)f2bf(r[6]) | ((uint32_t)f2bf(r[7]) << 16);
    *(uint4*)((uint16_t*)out + idx) = vo;
  } else {
    float4* of = (float4*)((float*)out + idx);
    of[0] = make_float4(r[0], r[1], r[2], r[3]);
    of[1] = make_float4(r[4], r[5], r[6], r[7]);
  }
}

// ---------------------------------------------------------------------------
extern "C" void kernel_launch(void* const* d_in, const int* in_sizes, int n_in,
                              void* d_out, int out_size, void* d_ws, size_t ws_size,
                              hipStream_t stream) {
  const void* x = d_in[0];
  const void *w1 = d_in[1], *b1 = d_in[2], *w2 = d_in[3], *b2 = d_in[4];
  const void *w3 = d_in[5], *b3 = d_in[6], *w4 = d_in[7], *b4 = d_in[8];
  const void *w5 = d_in[9], *b5 = d_in[10], *w6 = d_in[11], *b6 = d_in[12];
  const void *w7 = d_in[13], *b7 = d_in[14], *w8 = d_in[15], *b8 = d_in[16];
  const void *w9 = d_in[17], *b9 = d_in[18];
  const void *g11 = d_in[19], *be11 = d_in[20], *g12 = d_in[21], *be12 = d_in[22];
  const void *g2 = d_in[23], *be2 = d_in[24];

  char* ws = (char*)d_ws;
  size_t off = 0;
  auto alloc = [&](size_t bytes) -> char* {
    char* p = ws + off;
    off = (off + bytes + 255) & ~(size_t)255;
    return p;
  };
  const size_t xp_bytes = (size_t)16 * 34 * 34 * 512 * 2;   // 18.94 MB
  const size_t y_bytes = (size_t)16 * 256 * 64 * 64 * 2;    // 33.55 MB (planar: 4*16*256*1024)
  const size_t u_bytes = (size_t)16 * 66 * 66 * 256 * 2;    // 35.68 MB
  const size_t Wp_bytes = (size_t)512 * 12800 * 2;          // 13.11 MB (packed classes)

  uint32_t* flag = (uint32_t*)alloc(256);
  uint16_t* Wp9 = (uint16_t*)alloc((size_t)256 * 2304 * 2);
  float* bpk = (float*)alloc(2048 * 4);
  float* b9pk = (float*)alloc(256 * 4);
  float2* st1a = (float2*)alloc(256 * 8);
  float2* st1b = (float2*)alloc(256 * 8);
  float2* st2 = (float2*)alloc(256 * 8);
  uint16_t* y1 = (uint16_t*)alloc(y_bytes);
  uint16_t* y2 = (uint16_t*)alloc(y_bytes);
  // union region: {Wp + xp} (gemm1 inputs) before gemm1; u (conv9 input) after
  size_t wpal = (Wp_bytes + 255) & ~(size_t)255;
  size_t region_bytes = wpal + xp_bytes;
  if (region_bytes < u_bytes) region_bytes = u_bytes;
  char* region = alloc(region_bytes);
  uint16_t* Wp = (uint16_t*)region;
  uint16_t* xp = (uint16_t*)(region + wpal);
  uint16_t* u = (uint16_t*)region;  // overlays Wp+xp, both dead after gemm1
  uint16_t* z = y1;                 // overlays y1, dead after u_fill
  // total footprint ~103 MB

  detect_dtype<<<1, 256, 0, stream>>>((const uint32_t*)x, flag);

  // fused prep: pad_x (512) | pack_w_unpool (512) | pack_w9+bias (2304)
  prep<<<3328, 256, 0, stream>>>(x, w1, w2, w3, w4, w5, w6, w7, w8, w9,
                                 b1, b2, b3, b4, b5, b6, b7, b8, b9, flag,
                                 xp, Wp, Wp9, bpk, b9pk);

  // unpool GEMM: 2048 blocks = 4 classes x (4 mt x 128 nt), class-major
  gemm_unpool<<<2048, 256, 0, stream>>>(Wp, xp, bpk, y1, y2);

  // BN stats for y1 and y2 in one launch
  bn_stats2<<<512, 256, 0, stream>>>(y1, y2, g11, be11, g12, be12, flag, st1a, st1b);

  // u_fill: one block per (b,h); zeroes u borders itself (no memset)
  u_fill<<<1024, 256, 0, stream>>>(y1, st1a, u);

  // conv9 GEMM: 1024 blocks = 2 mt x 512 nt; z aliases y1 (dead after u_fill)
  gemm_conv9<<<1024, 256, 0, stream>>>(Wp9, u, b9pk, z, nullptr);

  bn_stats<<<256, 256, 0, stream>>>(z, g2, be2, flag, st2, 2048);

  final_kernel<<<8192, 256, 0, stream>>>(z, y2, st2, st1b, flag, d_out);
}